// Round 7
// baseline (214.155 us; speedup 1.0000x reference)
//
#include <hip/hip_runtime.h>
#include <hip/hip_bf16.h>

// OTNoiseGate: B=8192, E=8, D=512, P=32, eps=0.05, 50 Sinkhorn iters.
// R7: SPLIT. Kernel 1 (cost): barrier-free MFMA cost GEMM (R6 K-loop),
// writes per-problem cost rows [c0[32] c1[32]] to d_ws and retires -> waves
// stream memory without a serial Sinkhorn tail. Kernel 2 (sinkhorn):
// 2 lanes/problem, 16 p in registers, only DPP xor-1 shuffles (no 120-cyc
// LDS-pipe bpermute), ns=2 scalar recurrence + ballot early-exit.

#define EXP2F(x) __builtin_amdgcn_exp2f(x)
#define LOG2F(x) __builtin_amdgcn_logf(x)   // v_log_f32 = log2
#define RCPF(x)  __builtin_amdgcn_rcpf(x)

typedef __bf16 bf16x8 __attribute__((ext_vector_type(8)));
typedef float  f32x4  __attribute__((ext_vector_type(4)));

#define BDIM 8192
#define EDIM 8
#define DDIM 512
#define PDIM 32
#define BPB  32             // problems per block (8 per wave x 4 waves)
#define NTHR 256
#define PFD  8              // prefetch depth: 16KB/wave in flight
#define TSTR 68             // LDS transpose-tile row stride (floats)
#define C_SCALE 28.853900817779268f   // log2(e)/eps
#define LOG2E   1.4426950408889634f

__device__ __forceinline__ bf16x8 cvt2(float4 a, float4 b) {
  bf16x8 r;
  r[0] = (__bf16)a.x; r[1] = (__bf16)a.y; r[2] = (__bf16)a.z; r[3] = (__bf16)a.w;
  r[4] = (__bf16)b.x; r[5] = (__bf16)b.y; r[6] = (__bf16)b.z; r[7] = (__bf16)b.w;
  return r;
}

// ===== Kernel 1: cost GEMM ===================================================
__global__ __launch_bounds__(NTHR, 3)
void cost_kernel(const float* __restrict__ tokens,
                 const float* __restrict__ protos,
                 const int*   __restrict__ fullIndexPtr,
                 float*       __restrict__ wsC) {
  const int fi = fullIndexPtr[0];
  const int e  = blockIdx.x & (EDIM - 1);      // chunk-major: anchor L3 reuse
  const int b0 = (blockIdx.x >> 3) * BPB;
  if (e == fi) return;                         // handled by sinkhorn_kernel

  __shared__ __align__(16) __bf16 sB[64 * PDIM * 8];  // [oct][p][8] = 32 KiB
  __shared__ float sPNp[8][PDIM];                     // proto-norm partials
  __shared__ __align__(16) float sT[4][8][TSTR];      // wave transpose tiles

  const int t  = threadIdx.x;
  const int l  = t & 63;
  const int w  = t >> 6;              // wave 0..3 -> problems b0+8w .. +7
  const int fr = l & 15;              // fragment lane index (M-row / N-col)
  const int q4 = l >> 4;              // k-slice selector (0..3)

  // A-fragment pointer: M-rows 0-7 tokens (c0), 8-15 anchors (c1)
  const int bRow = b0 + 8 * w + (fr & 7);
  const int eSel = (fr < 8) ? e : fi;
  const float4* rp4 = (const float4*)(tokens + ((size_t)bRow * EDIM + eSel) * DDIM);

  // prefetch chunks 0..PFD-1 (in flight during proto staging + barrier drain)
  float4 buf[PFD][2];
  #pragma unroll
  for (int c = 0; c < PFD; ++c) {
    buf[c][0] = rp4[c * 8 + q4 * 2];
    buf[c][1] = rp4[c * 8 + q4 * 2 + 1];
  }

  // stage protos[e] -> bf16 LDS + fp32 norm partials
  {
    const float4* pG4 = (const float4*)(protos + (size_t)e * PDIM * DDIM);
    const int p  = t & 31;
    const int oh = t >> 5;            // 0..7
    float pnp = 0.f;
    #pragma unroll
    for (int pass = 0; pass < 8; ++pass) {
      int oct = oh * 8 + pass;        // k = [oct*8, oct*8+8)
      float4 a = pG4[p * 128 + oct * 2];
      float4 b = pG4[p * 128 + oct * 2 + 1];
      pnp += a.x*a.x + a.y*a.y + a.z*a.z + a.w*a.w
           + b.x*b.x + b.y*b.y + b.z*b.z + b.w*b.w;
      *(bf16x8*)&sB[(oct * PDIM + p) * 8] = cvt2(a, b);
    }
    sPNp[oh][p] = pnp;
  }
  __syncthreads();                    // the ONLY barrier

  // K-loop: 8-deep pipelined global A, LDS B, 2 MFMA/chunk
  f32x4 acc0 = (f32x4){0.f, 0.f, 0.f, 0.f};
  f32x4 acc1 = (f32x4){0.f, 0.f, 0.f, 0.f};
  float ss = 0.f;                     // partial ||row fr||^2 over this lane's k

  #pragma unroll
  for (int kc = 0; kc < 16; ++kc) {
    float4 ca0 = buf[kc % PFD][0];
    float4 ca1 = buf[kc % PFD][1];
    if (kc < 16 - PFD) {              // refill slot; lands PFD chunks ahead
      buf[kc % PFD][0] = rp4[(kc + PFD) * 8 + q4 * 2];
      buf[kc % PFD][1] = rp4[(kc + PFD) * 8 + q4 * 2 + 1];
    }
    ss += ca0.x*ca0.x + ca0.y*ca0.y + ca0.z*ca0.z + ca0.w*ca0.w
        + ca1.x*ca1.x + ca1.y*ca1.y + ca1.z*ca1.z + ca1.w*ca1.w;
    bf16x8 aF  = cvt2(ca0, ca1);
    bf16x8 bF0 = *(const bf16x8*)&sB[((kc * 4 + q4) * PDIM + fr) * 8];
    bf16x8 bF1 = *(const bf16x8*)&sB[((kc * 4 + q4) * PDIM + 16 + fr) * 8];
    acc0 = __builtin_amdgcn_mfma_f32_16x16x32_bf16(aF, bF0, acc0, 0, 0, 0);
    acc1 = __builtin_amdgcn_mfma_f32_16x16x32_bf16(aF, bF1, acc1, 0, 0, 0);
  }

  // row norms + proto norms
  ss += __shfl_xor(ss, 16);
  ss += __shfl_xor(ss, 32);           // lanes (fr,*) now hold ||row fr||^2
  float pn_a = 0.f, pn_b = 0.f;       // proto norms for cols fr, 16+fr
  #pragma unroll
  for (int o = 0; o < 8; ++o) {
    pn_a += sPNp[o][fr];
    pn_b += sPNp[o][16 + fr];
  }

  // epilogue: cost -> wave-private LDS tile [prob][c0[32] c1[32]]
  #pragma unroll
  for (int reg = 0; reg < 4; ++reg) {
    int row  = q4 * 4 + reg;          // C/D: row=(l>>4)*4+reg, col=fr
    int prob = row & 7;
    int half = row >> 3;              // 0: token row (c0), 1: anchor row (c1)
    float nrm = __shfl(ss, row);
    sT[w][prob][half * 32 + fr]      = fmaxf(nrm - 2.f * acc0[reg] + pn_a, 0.f);
    sT[w][prob][half * 32 + 16 + fr] = fmaxf(nrm - 2.f * acc1[reg] + pn_b, 0.f);
  }
  // DS pipe is in-order per wave: reads below see the writes above.

  // coalesced store: wave's 8 problems x 64 floats -> ws[(e*B + b)*64 ...]
  {
    const size_t pbBase = (size_t)e * BDIM + b0 + 8 * w;
    const int prob = l >> 3;
    const int seg  = l & 7;
    float4 v0 = *(const float4*)&sT[w][prob][seg * 8];
    float4 v1 = *(const float4*)&sT[w][prob][seg * 8 + 4];
    float4* dst = (float4*)(wsC + (pbBase + prob) * 64 + seg * 8);
    dst[0] = v0;
    dst[1] = v1;
  }
}

// ===== Kernel 2: Sinkhorn ====================================================
__global__ __launch_bounds__(NTHR, 6)
void sinkhorn_kernel(const float* __restrict__ wsC,
                     const int*   __restrict__ fullIndexPtr,
                     float*       __restrict__ out) {
  const int fi = fullIndexPtr[0];
  const int t  = threadIdx.x;
  const int pb = blockIdx.x * (NTHR / 2) + (t >> 1);   // pair index e*B+b
  const int h  = t & 1;               // half: p in [16h, 16h+16)
  const int e  = pb >> 13;
  const int b  = pb & (BDIM - 1);
  float* outVal = out;                // validity (B,E,1)
  float* outOt  = out + BDIM * EDIM;  // ot_cost  (B,E)

  if (e == fi) {                      // block-uniform (8192 pairs per e)
    if (h == 0) {
      outVal[b * EDIM + e] = 1.0f;
      outOt [b * EDIM + e] = 0.0f;
    }
    return;
  }

  // load this lane's 16 c0 + 16 c1
  float c0[16], c1[16];
  {
    const float4* base = (const float4*)(wsC + (size_t)pb * 64);
    #pragma unroll
    for (int r = 0; r < 4; ++r) {
      float4 v0 = base[h * 4 + r];
      float4 v1 = base[8 + h * 4 + r];
      c0[4*r] = v0.x; c0[4*r+1] = v0.y; c0[4*r+2] = v0.z; c0[4*r+3] = v0.w;
      c1[4*r] = v1.x; c1[4*r+1] = v1.y; c1[4*r+2] = v1.z; c1[4*r+3] = v1.w;
    }
  }

  float W[16], dc[16];
  float sum0 = 0.f, mA = -1e30f, mB = -1e30f;
  #pragma unroll
  for (int r = 0; r < 16; ++r) {
    float ka = -c0[r] * C_SCALE, kb = -c1[r] * C_SCALE;
    dc[r] = c1[r] - c0[r];
    sum0 += c0[r];
    mA = fmaxf(mA, ka);
    mB = fmaxf(mB, kb);
  }
  mA = fmaxf(mA, __shfl_xor(mA, 1));      // DPP, partner lane
  mB = fmaxf(mB, __shfl_xor(mB, 1));
  float sa = 0.f, sb = 0.f;
  #pragma unroll
  for (int r = 0; r < 16; ++r) {
    float ka = -c0[r] * C_SCALE, kb = -c1[r] * C_SCALE;
    sa += EXP2F(ka - mA);
    sb += EXP2F(kb - mB);
    W[r] = EXP2F(C_SCALE * dc[r]);    // 2^(k0-k1)
  }
  sa += __shfl_xor(sa, 1);
  sb += __shfl_xor(sb, 1);
  sum0 += __shfl_xor(sum0, 1);
  // iteration 1 (reference: lv=0): delta1 = lse2(k1) - lse2(k0)
  float delta = (mB + LOG2F(sb)) - (mA + LOG2F(sa));

  // iterations 2..50 with fp32-noise early exit (bit-equivalent to full run)
  for (int it = 0; it < 49; ++it) {
    float s2 = EXP2F(delta);
    float T = 0.f;
    #pragma unroll
    for (int r = 0; r < 16; ++r)
      T += RCPF(__builtin_fmaf(W[r], s2, 1.0f));   // sigma_p
    T += __shfl_xor(T, 1);            // in (0,32)
    float upd = LOG2F(T) - LOG2F(32.0f - T);
    delta += upd;
    if (__ballot(fabsf(upd) > 5e-7f) == 0ull) break;
  }

  // final transport & outputs
  float s2 = EXP2F(delta), sv = 0.f;
  #pragma unroll
  for (int r = 0; r < 16; ++r)
    sv += RCPF(__builtin_fmaf(W[r], s2, 1.0f)) * dc[r];
  sv += __shfl_xor(sv, 1);
  if (h == 0) {
    float ot  = (sum0 + sv) * 0.03125f;
    float val = RCPF(1.0f + EXP2F(LOG2E * 6.0f * (ot - 0.25f)));
    outVal[b * EDIM + e] = val;
    outOt [b * EDIM + e] = ot;
  }
}

extern "C" void kernel_launch(void* const* d_in, const int* in_sizes, int n_in,
                              void* d_out, int out_size, void* d_ws, size_t ws_size,
                              hipStream_t stream) {
  const float* tokens = (const float*)d_in[0];   // (8192, 8, 512) fp32
  const float* protos = (const float*)d_in[1];   // (8, 32, 512) fp32
  const int*   fidx   = (const int*)d_in[2];     // scalar
  float* out = (float*)d_out;                    // 65536 validity + 65536 ot
  float* wsC = (float*)d_ws;                     // 65536 x 64 floats = 16.8MB

  dim3 gridC((BDIM / BPB) * EDIM);               // 2048 blocks, chunk-major
  cost_kernel<<<gridC, NTHR, 0, stream>>>(tokens, protos, fidx, wsC);
  dim3 gridS(BDIM * EDIM / (NTHR / 2));          // 512 blocks
  sinkhorn_kernel<<<gridS, NTHR, 0, stream>>>(wsC, fidx, out);
}